// Round 7
// baseline (26.013 us; speedup 1.0000x reference)
//
#include <hip/hip_runtime.h>

// LengthRegulator: B=32, T=512, D=384, max_len=2048 (fixed by setup_inputs).
// Output flat in d_out (float32): out[B][max_len][D], then mel_len[B] as float.
// R6: grid (64,32) = 2048 blocks = exactly 8 blocks/CU -> whole grid resident
// from t=0 (no second dispatch generation); each block does one scan and
// writes 32 output rows (2x amortization vs R4). NT stores (R5 showed +3%).

#define T_IN   512
#define D_DIM  384
#define D4     (D_DIM / 4)     // 96 float4 per row
#define MAXLEN 2048
#define B_SZ   32
#define ROWS_PER_BLOCK 32

typedef float f32x4 __attribute__((ext_vector_type(4)));

__global__ __launch_bounds__(256) void lr_fused_kernel(const float* __restrict__ x,
                                                       const int* __restrict__ dur,
                                                       float* __restrict__ out,
                                                       float* __restrict__ mel_out) {
    __shared__ int scum[T_IN];
    __shared__ int wsum[4];
    __shared__ int sidx[ROWS_PER_BLOCK];
    const int b = blockIdx.y;
    const int tid = threadIdx.x;
    const int lane = tid & 63;
    const int wave = tid >> 6;

    // ---- Scan of duration[b][0..511]: pair-sum + wave shuffle scan (2 barriers).
    int2 d2 = ((const int2*)(dur + b * T_IN))[tid];   // coalesced 8B/thread
    const int pair = d2.x + d2.y;
    int v = pair;
    #pragma unroll
    for (int off = 1; off < 64; off <<= 1) {
        int u = __shfl_up(v, off, 64);
        if (lane >= off) v += u;
    }
    if (lane == 63) wsum[wave] = v;
    __syncthreads();
    int wprefix = 0;
    #pragma unroll
    for (int w = 0; w < 4; ++w) wprefix += (w < wave) ? wsum[w] : 0;
    v += wprefix;                                     // inclusive pair-prefix over 256
    const int excl = v - pair;
    scum[2 * tid]     = excl + d2.x;                  // 2-way bank alias: free
    scum[2 * tid + 1] = excl + d2.x + d2.y;
    __syncthreads();

    const int mel = scum[T_IN - 1];
    if (blockIdx.x == 0 && tid == 0) mel_out[b] = (float)mel;

    // ---- 32 binary searches: idx = first i with cum[i] > p (searchsorted 'right').
    if (tid < ROWS_PER_BLOCK) {
        const int p = blockIdx.x * ROWS_PER_BLOCK + tid;
        int lo = 0, hi = T_IN;
        while (lo < hi) {
            int mid = (lo + hi) >> 1;
            if (scum[mid] <= p) lo = mid + 1; else hi = mid;
        }
        if (lo > T_IN - 1) lo = T_IN - 1;             // clip
        sidx[tid] = (p < mel) ? lo : -1;              // -1 => zeros
    }
    __syncthreads();

    // ---- Copy 32 rows x 96 float4 = 3072 f32x4, 12/thread, coalesced NT stores.
    const f32x4* __restrict__ x4 = (const f32x4*)x + (size_t)b * T_IN * D4;
    f32x4* __restrict__ out4 =
        (f32x4*)out + ((size_t)b * MAXLEN + (size_t)blockIdx.x * ROWS_PER_BLOCK) * D4;
    #pragma unroll
    for (int i = 0; i < 12; ++i) {
        int flat = i * 256 + tid;
        int row = flat / D4;            // constant divide -> magic multiply
        int chunk = flat - row * D4;
        int idx = sidx[row];
        f32x4 val = (f32x4)(0.f);
        if (idx >= 0)
            val = x4[(size_t)idx * D4 + chunk];
        __builtin_nontemporal_store(val, &out4[flat]);
    }
}

extern "C" void kernel_launch(void* const* d_in, const int* in_sizes, int n_in,
                              void* d_out, int out_size, void* d_ws, size_t ws_size,
                              hipStream_t stream) {
    const float* x = (const float*)d_in[0];
    const int* dur = (const int*)d_in[1];
    // d_in[2] = max_len (2048), fixed by setup; grid computed host-side.

    float* out = (float*)d_out;
    float* mel_out = out + (size_t)B_SZ * MAXLEN * D_DIM;  // tail: mel_len as float

    dim3 grid(MAXLEN / ROWS_PER_BLOCK, B_SZ);  // (64, 32) = 2048 blocks
    lr_fused_kernel<<<grid, 256, 0, stream>>>(x, dur, out, mel_out);
}

// Round 8
// 24.863 us; speedup vs baseline: 1.0463x; 1.0463x over previous
//
#include <hip/hip_runtime.h>

// LengthRegulator: B=32, T=512, D=384, max_len=2048 (fixed by setup_inputs).
// Output flat in d_out (float32): out[B][max_len][D], then mel_len[B] as float.
// R7: R4 geometry (4096 blocks, 16 rows/block, NT stores) + XCD-aware block
// remap: xcd = id&7 owns batches 4*xcd..4*xcd+3, so each XCD's L2 (4 MB) holds
// its 4 batches' x slices (3.1 MB) resident -> gather reads become L2 hits.

#define T_IN   512
#define D_DIM  384
#define D4     (D_DIM / 4)     // 96 float4 per row
#define MAXLEN 2048
#define B_SZ   32
#define ROWS_PER_BLOCK 16

typedef float f32x4 __attribute__((ext_vector_type(4)));

__global__ __launch_bounds__(256) void lr_fused_kernel(const float* __restrict__ x,
                                                       const int* __restrict__ dur,
                                                       float* __restrict__ out,
                                                       float* __restrict__ mel_out) {
    __shared__ int scum[T_IN];
    __shared__ int wsum[4];
    __shared__ int sidx[ROWS_PER_BLOCK];
    const int tid = threadIdx.x;
    const int lane = tid & 63;
    const int wave = tid >> 6;

    // ---- XCD-aware remap: consecutive blockIdx round-robin across 8 XCDs.
    // Pin batch b to XCD b>>2: per-XCD x working set = 4 * 786 KB = 3.1 MB < 4 MB L2.
    const int id = blockIdx.x;          // 0..4095
    const int xcd = id & 7;
    const int j = id >> 3;              // 0..511 within XCD
    const int b = xcd * 4 + (j >> 7);   // 4 batches per XCD
    const int pg = j & 127;             // position group (16 rows each)

    // ---- Scan of duration[b][0..511]: pair-sum + wave shuffle scan (2 barriers).
    int2 d2 = ((const int2*)(dur + b * T_IN))[tid];   // coalesced 8B/thread
    const int pair = d2.x + d2.y;
    int v = pair;
    #pragma unroll
    for (int off = 1; off < 64; off <<= 1) {
        int u = __shfl_up(v, off, 64);
        if (lane >= off) v += u;
    }
    if (lane == 63) wsum[wave] = v;
    __syncthreads();
    int wprefix = 0;
    #pragma unroll
    for (int w = 0; w < 4; ++w) wprefix += (w < wave) ? wsum[w] : 0;
    v += wprefix;                                     // inclusive pair-prefix over 256
    const int excl = v - pair;
    scum[2 * tid]     = excl + d2.x;                  // 2-way bank alias: free
    scum[2 * tid + 1] = excl + d2.x + d2.y;
    __syncthreads();

    const int mel = scum[T_IN - 1];
    if (pg == 0 && tid == 0) mel_out[b] = (float)mel;

    // ---- 16 binary searches: idx = first i with cum[i] > p (searchsorted 'right').
    if (tid < ROWS_PER_BLOCK) {
        const int p = pg * ROWS_PER_BLOCK + tid;
        int lo = 0, hi = T_IN;
        while (lo < hi) {
            int mid = (lo + hi) >> 1;
            if (scum[mid] <= p) lo = mid + 1; else hi = mid;
        }
        if (lo > T_IN - 1) lo = T_IN - 1;             // clip
        sidx[tid] = (p < mel) ? lo : -1;              // -1 => zeros
    }
    __syncthreads();

    // ---- Copy 16 rows x 96 float4, 6 float4/thread, coalesced NT stores.
    const f32x4* __restrict__ x4 = (const f32x4*)x + (size_t)b * T_IN * D4;
    f32x4* __restrict__ out4 =
        (f32x4*)out + ((size_t)b * MAXLEN + (size_t)pg * ROWS_PER_BLOCK) * D4;
    #pragma unroll
    for (int i = 0; i < 6; ++i) {
        int flat = i * 256 + tid;
        int row = flat / D4;            // constant divide -> magic multiply
        int chunk = flat - row * D4;
        int idx = sidx[row];
        f32x4 val = (f32x4)(0.f);
        if (idx >= 0)
            val = x4[(size_t)idx * D4 + chunk];
        __builtin_nontemporal_store(val, &out4[flat]);
    }
}

extern "C" void kernel_launch(void* const* d_in, const int* in_sizes, int n_in,
                              void* d_out, int out_size, void* d_ws, size_t ws_size,
                              hipStream_t stream) {
    const float* x = (const float*)d_in[0];
    const int* dur = (const int*)d_in[1];
    // d_in[2] = max_len (2048), fixed by setup; grid computed host-side.

    float* out = (float*)d_out;
    float* mel_out = out + (size_t)B_SZ * MAXLEN * D_DIM;  // tail: mel_len as float

    lr_fused_kernel<<<4096, 256, 0, stream>>>(x, dur, out, mel_out);
}

// Round 9
// 24.384 us; speedup vs baseline: 1.0668x; 1.0196x over previous
//
#include <hip/hip_runtime.h>

// LengthRegulator: B=32, T=512, D=384, max_len=2048 (fixed by setup_inputs).
// Output flat in d_out (float32): out[B][max_len][D], then mel_len[B] as float.
// R8: R4 structure, finer blocks: grid (256,32) = 8192 blocks x 8 rows each.
// Scan prologue is hidden (R4 A/B); finer blocks pack the dispatch tail better.

#define T_IN   512
#define D_DIM  384
#define D4     (D_DIM / 4)     // 96 float4 per row
#define MAXLEN 2048
#define B_SZ   32
#define ROWS_PER_BLOCK 8

typedef float f32x4 __attribute__((ext_vector_type(4)));

__global__ __launch_bounds__(256) void lr_fused_kernel(const float* __restrict__ x,
                                                       const int* __restrict__ dur,
                                                       float* __restrict__ out,
                                                       float* __restrict__ mel_out) {
    __shared__ int scum[T_IN];
    __shared__ int wsum[4];
    __shared__ int sidx[ROWS_PER_BLOCK];
    const int b = blockIdx.y;
    const int tid = threadIdx.x;
    const int lane = tid & 63;
    const int wave = tid >> 6;

    // ---- Scan of duration[b][0..511]: pair-sum + wave shuffle scan (2 barriers).
    int2 d2 = ((const int2*)(dur + b * T_IN))[tid];   // coalesced 8B/thread
    const int pair = d2.x + d2.y;
    int v = pair;
    #pragma unroll
    for (int off = 1; off < 64; off <<= 1) {
        int u = __shfl_up(v, off, 64);
        if (lane >= off) v += u;
    }
    if (lane == 63) wsum[wave] = v;
    __syncthreads();
    int wprefix = 0;
    #pragma unroll
    for (int w = 0; w < 4; ++w) wprefix += (w < wave) ? wsum[w] : 0;
    v += wprefix;                                     // inclusive pair-prefix over 256
    const int excl = v - pair;
    scum[2 * tid]     = excl + d2.x;                  // 2-way bank alias: free
    scum[2 * tid + 1] = excl + d2.x + d2.y;
    __syncthreads();

    const int mel = scum[T_IN - 1];
    if (blockIdx.x == 0 && tid == 0) mel_out[b] = (float)mel;

    // ---- 8 binary searches: idx = first i with cum[i] > p (searchsorted 'right').
    if (tid < ROWS_PER_BLOCK) {
        const int p = blockIdx.x * ROWS_PER_BLOCK + tid;
        int lo = 0, hi = T_IN;
        while (lo < hi) {
            int mid = (lo + hi) >> 1;
            if (scum[mid] <= p) lo = mid + 1; else hi = mid;
        }
        if (lo > T_IN - 1) lo = T_IN - 1;             // clip
        sidx[tid] = (p < mel) ? lo : -1;              // -1 => zeros
    }
    __syncthreads();

    // ---- Copy 8 rows x 96 float4 = 768 f32x4, 3/thread, coalesced NT stores.
    const f32x4* __restrict__ x4 = (const f32x4*)x + (size_t)b * T_IN * D4;
    f32x4* __restrict__ out4 =
        (f32x4*)out + ((size_t)b * MAXLEN + (size_t)blockIdx.x * ROWS_PER_BLOCK) * D4;
    #pragma unroll
    for (int i = 0; i < 3; ++i) {
        int flat = i * 256 + tid;
        int row = flat / D4;            // constant divide -> magic multiply
        int chunk = flat - row * D4;
        int idx = sidx[row];
        f32x4 val = (f32x4)(0.f);
        if (idx >= 0)
            val = x4[(size_t)idx * D4 + chunk];
        __builtin_nontemporal_store(val, &out4[flat]);
    }
}

extern "C" void kernel_launch(void* const* d_in, const int* in_sizes, int n_in,
                              void* d_out, int out_size, void* d_ws, size_t ws_size,
                              hipStream_t stream) {
    const float* x = (const float*)d_in[0];
    const int* dur = (const int*)d_in[1];
    // d_in[2] = max_len (2048), fixed by setup; grid computed host-side.

    float* out = (float*)d_out;
    float* mel_out = out + (size_t)B_SZ * MAXLEN * D_DIM;  // tail: mel_len as float

    dim3 grid(MAXLEN / ROWS_PER_BLOCK, B_SZ);  // (256, 32) = 8192 blocks
    lr_fused_kernel<<<grid, 256, 0, stream>>>(x, dur, out, mel_out);
}